// Round 2
// baseline (306.785 us; speedup 1.0000x reference)
//
#include <hip/hip_runtime.h>
#include <hip/hip_bf16.h>

// Problem: B=4, S=2048, E=1024, H=16, D=64, WIN=512.
// out = ( swa_alibi( split_heads(x @ w_in^T) ) merged ) @ w_out^T
//
// Inputs may arrive as float32 (reference dtype) or bf16 (harness-converted).
// A detector kernel sniffs the encoding and conversion kernels normalize to
// bf16 workspace buffers; the final GEMM stores f32 or bf16 per the flag.
//
// Pipeline:
//   k0: detect dtype -> flag; convert x, w_in, w_out -> bf16 in ws
//   k1: qkv[8192,3072] = x[8192,1024] @ w_in[3072,1024]^T      (gemm_bt)
//   k2: o[8192,1024]   = sliding-window attention per (b,h,qtile)
//   k3: out[8192,1024] = o @ w_out[1024,1024]^T                (gemm_bt)

typedef __bf16 bf16x8 __attribute__((ext_vector_type(8)));
typedef float f32x4 __attribute__((ext_vector_type(4)));

__device__ __forceinline__ f32x4 mfma16(bf16x8 a, bf16x8 b, f32x4 c) {
    return __builtin_amdgcn_mfma_f32_16x16x32_bf16(a, b, c, 0, 0, 0);
}

__global__ void init_flag(int* flag) { *flag = 0; }

// If the buffer is really float32, odd bf16-halfwords are mantissa garbage:
// exponent bits ~uniform -> values >= 2^14 (e >= 0x8D) occur with p~0.45.
// Genuine bf16 weights (|w| <= ~0.2) never exceed e=126.
__global__ void detect_f32(const unsigned short* __restrict__ w, int n,
                           int* flag) {
    int i = blockIdx.x * blockDim.x + threadIdx.x;
    int hit = 0;
    for (; i < n; i += gridDim.x * blockDim.x) {
        int e = (w[i] >> 7) & 0xFF;
        if (e >= 0x8D) hit = 1;
    }
    unsigned long long m = __ballot(hit);
    if (m != 0 && (threadIdx.x & 63) == 0) atomicOr(flag, 1);
}

__global__ void cvt_bf16(const void* __restrict__ src, __bf16* __restrict__ dst,
                         int n, const int* __restrict__ flag) {
    const bool f = (*flag != 0);
    int i = blockIdx.x * blockDim.x + threadIdx.x;
    const int stride = gridDim.x * blockDim.x;
    if (f) {
        const float* s = (const float*)src;
        for (; i < n; i += stride) dst[i] = (__bf16)s[i];
    } else {
        const __bf16* s = (const __bf16*)src;
        for (; i < n; i += stride) dst[i] = s[i];
    }
}

// C[M,N] = A[M,K] @ Bt[N,K]^T, bf16 in, fp32 accumulate.
// 128x128 tile, BK=32, 4 waves each 64x64 (4x4 of 16x16x32 MFMA).
// Store bf16 to Cb, unless (flagp && *flagp) -> store f32 to Cf.
__global__ __launch_bounds__(256, 2) void gemm_bt(
        const __bf16* __restrict__ A, const __bf16* __restrict__ Bt,
        __bf16* __restrict__ Cb, float* __restrict__ Cf,
        const int* __restrict__ flagp, int M, int N, int K) {
    // pitch 40 elems = 80 B (16B-aligned rows; 2-way bank aliasing = free)
    __shared__ __align__(16) __bf16 As[128 * 40];
    __shared__ __align__(16) __bf16 Bs[128 * 40];

    const int t = threadIdx.x;
    const int lane = t & 63;
    const int w = t >> 6;
    const int wr = w >> 1, wc = w & 1;
    const int q4 = lane >> 4, l16 = lane & 15;
    const int m0 = blockIdx.y * 128, n0 = blockIdx.x * 128;
    const bool f32out = flagp && (*flagp != 0);

    f32x4 acc[4][4] = {};

    for (int k0 = 0; k0 < K; k0 += 32) {
#pragma unroll
        for (int p = 0; p < 2; ++p) {
            int u = p * 256 + t;           // 0..511
            int row = u >> 2, ch = u & 3;  // 4 x 16B chunks per 64B row
            *(uint4*)&As[row * 40 + ch * 8] =
                *(const uint4*)&A[(size_t)(m0 + row) * K + k0 + ch * 8];
            *(uint4*)&Bs[row * 40 + ch * 8] =
                *(const uint4*)&Bt[(size_t)(n0 + row) * K + k0 + ch * 8];
        }
        __syncthreads();

        bf16x8 af[4], bfr[4];
#pragma unroll
        for (int mt = 0; mt < 4; ++mt)
            af[mt] = *(const bf16x8*)&As[(wr * 64 + mt * 16 + l16) * 40 + q4 * 8];
#pragma unroll
        for (int nt = 0; nt < 4; ++nt)
            bfr[nt] = *(const bf16x8*)&Bs[(wc * 64 + nt * 16 + l16) * 40 + q4 * 8];
#pragma unroll
        for (int mt = 0; mt < 4; ++mt)
#pragma unroll
            for (int nt = 0; nt < 4; ++nt)
                acc[mt][nt] = mfma16(af[mt], bfr[nt], acc[mt][nt]);
        __syncthreads();
    }

    // epilogue: C/D layout col=lane&15, row=(lane>>4)*4+reg
#pragma unroll
    for (int mt = 0; mt < 4; ++mt)
#pragma unroll
        for (int nt = 0; nt < 4; ++nt) {
            int col = n0 + wc * 64 + nt * 16 + l16;
#pragma unroll
            for (int r = 0; r < 4; ++r) {
                int row = m0 + wr * 64 + mt * 16 + q4 * 4 + r;
                if (f32out)
                    Cf[(size_t)row * N + col] = acc[mt][nt][r];
                else
                    Cb[(size_t)row * N + col] = (__bf16)acc[mt][nt][r];
            }
        }
}

// Sliding-window causal attention with ALiBi, flash-style online softmax.
// grid = (S/128, H, B), block = 256 (4 waves; wave w owns queries w*32..+31).
__global__ __launch_bounds__(256, 2) void attn(
        const __bf16* __restrict__ qkv, __bf16* __restrict__ o) {
    constexpr int KP = 72;   // K-tile pitch (rows=key, cols=d)   128x72
    constexpr int VP = 136;  // Vt pitch     (rows=d, cols=key)    64x136
    constexpr int PP = 72;   // P pitch      (rows=query, cols=key half) 128x72
    __shared__ __align__(16) __bf16 Ks[128 * KP];
    __shared__ __align__(16) __bf16 Vts[64 * VP];
    __shared__ __align__(16) __bf16 Ps[128 * PP];

    const int qt = blockIdx.x, h = blockIdx.y, b = blockIdx.z;
    const int t = threadIdx.x;
    const int lane = t & 63, w = t >> 6;
    const int q4 = lane >> 4, l16 = lane & 15;
    const int q0 = qt * 128;

    const float L2E = 1.4426950408889634f;
    const float slope = exp2f(-(float)(h + 1) * 0.5f);  // exp2(-(h+1)*8/H), H=16
    const float scale2 = L2E * 0.125f;                  // L2E / sqrt(64)
    const float slope2 = slope * L2E;

    // Preload Q fragments from global (A-layout: m=lane&15, k=quad*8+j)
    bf16x8 qf[2][2];
    const size_t qbase = ((size_t)b * 2048 + q0) * 3072 + (size_t)h * 64;
#pragma unroll
    for (int mt = 0; mt < 2; ++mt)
#pragma unroll
        for (int kt = 0; kt < 2; ++kt)
            qf[mt][kt] = *(const bf16x8*)&qkv[qbase +
                (size_t)(w * 32 + mt * 16 + l16) * 3072 + kt * 32 + q4 * 8];

    f32x4 O[2][4] = {};
    float mrow[2][4], lrow[2][4];
#pragma unroll
    for (int mt = 0; mt < 2; ++mt)
#pragma unroll
        for (int r = 0; r < 4; ++r) { mrow[mt][r] = -1e30f; lrow[mt][r] = 0.0f; }

    const int nkt = (qt < 4 ? qt : 4) + 1;
    const int ktile0 = qt - (nkt - 1);

    for (int ki = 0; ki < nkt; ++ki) {
        const int k0 = (ktile0 + ki) * 128;
        const size_t kbase = ((size_t)b * 2048 + k0) * 3072 + 1024 + (size_t)h * 64;
        const size_t vbase = ((size_t)b * 2048 + k0) * 3072 + 2048 + (size_t)h * 64;

        // stage K [128 keys][64 d] natural; V transposed -> Vts [64 d][128 keys]
#pragma unroll
        for (int it = 0; it < 4; ++it) {
            int u = it * 256 + t;          // 0..1023
            int row = u >> 3, ch = u & 7;  // 8 x 16B chunks per 128B row
            *(uint4*)&Ks[row * KP + ch * 8] =
                *(const uint4*)&qkv[kbase + (size_t)row * 3072 + ch * 8];
            uint4 vv = *(const uint4*)&qkv[vbase + (size_t)row * 3072 + ch * 8];
            const __bf16* ve = (const __bf16*)&vv;
#pragma unroll
            for (int j = 0; j < 8; ++j)
                Vts[(ch * 8 + j) * VP + row] = ve[j];
        }
        __syncthreads();

        // S = Q K^T : per wave 2 mtiles x 8 ntiles, K-dim 64 = 2 frags
        f32x4 sc[2][8] = {};
#pragma unroll
        for (int kt = 0; kt < 2; ++kt) {
#pragma unroll
            for (int nt = 0; nt < 8; ++nt) {
                bf16x8 bk = *(const bf16x8*)&Ks[(nt * 16 + l16) * KP + kt * 32 + q4 * 8];
                sc[0][nt] = mfma16(qf[0][kt], bk, sc[0][nt]);
                sc[1][nt] = mfma16(qf[1][kt], bk, sc[1][nt]);
            }
        }

        // bias + mask + online softmax (log2 domain)
#pragma unroll
        for (int mt = 0; mt < 2; ++mt) {
            float mx[4];
#pragma unroll
            for (int r = 0; r < 4; ++r) {
                int qa = q0 + w * 32 + mt * 16 + q4 * 4 + r;
                mx[r] = -1e30f;
#pragma unroll
                for (int nt = 0; nt < 8; ++nt) {
                    int ka = k0 + nt * 16 + l16;
                    int delta = qa - ka;
                    float v = sc[mt][nt][r] * scale2 + slope2 * (float)delta;
                    v = (delta >= 0 && delta <= 512) ? v : -1e30f;
                    sc[mt][nt][r] = v;
                    mx[r] = fmaxf(mx[r], v);
                }
            }
#pragma unroll
            for (int off = 1; off < 16; off <<= 1)
#pragma unroll
                for (int r = 0; r < 4; ++r)
                    mx[r] = fmaxf(mx[r], __shfl_xor(mx[r], off, 16));

            float al[4];
#pragma unroll
            for (int r = 0; r < 4; ++r) {
                float mnew = fmaxf(mrow[mt][r], mx[r]);
                al[r] = exp2f(mrow[mt][r] - mnew);
                mrow[mt][r] = mnew;
            }
            float rs[4] = {0.f, 0.f, 0.f, 0.f};
#pragma unroll
            for (int nt = 0; nt < 8; ++nt)
#pragma unroll
                for (int r = 0; r < 4; ++r) {
                    float p = exp2f(sc[mt][nt][r] - mrow[mt][r]);
                    sc[mt][nt][r] = p;
                    rs[r] += p;
                }
#pragma unroll
            for (int off = 1; off < 16; off <<= 1)
#pragma unroll
                for (int r = 0; r < 4; ++r)
                    rs[r] += __shfl_xor(rs[r], off, 16);
#pragma unroll
            for (int r = 0; r < 4; ++r)
                lrow[mt][r] = lrow[mt][r] * al[r] + rs[r];
#pragma unroll
            for (int nt = 0; nt < 4; ++nt)
#pragma unroll
                for (int r = 0; r < 4; ++r)
                    O[mt][nt][r] *= al[r];
        }

        // PV in two 64-key halves: P (C/D layout) -> LDS -> A-layout; B from Vt.
        // Each wave touches only its own 32-row strip of Ps (per-wave in-order
        // DS pipe makes write->read safe without a barrier).
#pragma unroll
        for (int hh = 0; hh < 2; ++hh) {
#pragma unroll
            for (int mt = 0; mt < 2; ++mt)
#pragma unroll
                for (int nt = 0; nt < 4; ++nt)
#pragma unroll
                    for (int r = 0; r < 4; ++r)
                        Ps[(w * 32 + mt * 16 + q4 * 4 + r) * PP + nt * 16 + l16] =
                            (__bf16)sc[mt][hh * 4 + nt][r];
#pragma unroll
            for (int mt = 0; mt < 2; ++mt)
#pragma unroll
                for (int kt = 0; kt < 2; ++kt) {
                    bf16x8 pa = *(const bf16x8*)&Ps[(w * 32 + mt * 16 + l16) * PP +
                                                    kt * 32 + q4 * 8];
#pragma unroll
                    for (int nt = 0; nt < 4; ++nt) {
                        bf16x8 vb = *(const bf16x8*)&Vts[(nt * 16 + l16) * VP +
                                                         hh * 64 + kt * 32 + q4 * 8];
                        O[mt][nt] = mfma16(pa, vb, O[mt][nt]);
                    }
                }
        }
        __syncthreads();  // before restaging K/Vt next iteration
    }

    // epilogue: o[b, q, h*64 + d] = O / l  (guard: lrow>=1 whenever any valid key)
    const size_t obase = ((size_t)b * 2048 + q0) * 1024 + (size_t)h * 64;
#pragma unroll
    for (int mt = 0; mt < 2; ++mt)
#pragma unroll
        for (int r = 0; r < 4; ++r) {
            float inv = (lrow[mt][r] > 0.0f) ? 1.0f / lrow[mt][r] : 0.0f;
            int qrow = w * 32 + mt * 16 + q4 * 4 + r;
#pragma unroll
            for (int nt = 0; nt < 4; ++nt)
                o[obase + (size_t)qrow * 1024 + nt * 16 + l16] =
                    (__bf16)(O[mt][nt][r] * inv);
        }
}

extern "C" void kernel_launch(void* const* d_in, const int* in_sizes, int n_in,
                              void* d_out, int out_size, void* d_ws, size_t ws_size,
                              hipStream_t stream) {
    char* ws = (char*)d_ws;
    int* flag = (int*)ws;
    size_t off = 256;
    __bf16* xb  = (__bf16*)(ws + off); off += (size_t)8192 * 1024 * 2;
    __bf16* wib = (__bf16*)(ws + off); off += (size_t)3072 * 1024 * 2;
    __bf16* wob = (__bf16*)(ws + off); off += (size_t)1024 * 1024 * 2;
    __bf16* qkv = (__bf16*)(ws + off); off += (size_t)8192 * 3072 * 2;
    __bf16* o   = (__bf16*)(ws + off);

    init_flag<<<1, 1, 0, stream>>>(flag);
    int nscan = in_sizes[2] < 65536 ? in_sizes[2] : 65536;
    detect_f32<<<64, 256, 0, stream>>>((const unsigned short*)d_in[2], nscan, flag);

    cvt_bf16<<<2048, 256, 0, stream>>>(d_in[0], xb, 8192 * 1024, flag);
    cvt_bf16<<<1024, 256, 0, stream>>>(d_in[1], wib, 3072 * 1024, flag);
    cvt_bf16<<<512, 256, 0, stream>>>(d_in[2], wob, 1024 * 1024, flag);

    // qkv = x @ w_in^T
    gemm_bt<<<dim3(24, 64), 256, 0, stream>>>(xb, wib, qkv, nullptr, nullptr,
                                              8192, 3072, 1024);
    // attention
    attn<<<dim3(16, 16, 4), 256, 0, stream>>>(qkv, o);
    // out = o @ w_out^T (dtype per flag)
    gemm_bt<<<dim3(8, 64), 256, 0, stream>>>(o, wob, (__bf16*)d_out,
                                             (float*)d_out, flag,
                                             8192, 1024, 1024);
}